// Round 9
// baseline (233.451 us; speedup 1.0000x reference)
//
#include <hip/hip_runtime.h>

// Fused bilinear-2x-up -> leaky_relu(0.01) -> bilinear-0.5x-down
// == 3x3 clamped-edge stencil per output pixel:
//   up00 = .5625 e + .1875(b+d) + .0625 a   (etc. for the other 3 corners)
//   out  = 0.25 * sum(leaky_relu(up**))
//
// Ladder: R3 2x2 straight-line = 63 us; NT stores +21; 2x4 tile +19; XCD
// swizzles neutral; LDS halo neutral; 4-image 148-VGPR pipeline +39 (occ
// collapse); sched_barrier MLP fence = 60.5 us (WIN +2.5, kept).
//
// R12: amortize the per-wave cold-start stall. 2 tiles/thread (images b0,
// b0+8), 1.5-deep pipeline pinned by sched_barriers:
//   loadA(16) | loadB.top(8) | compute/storeA | loadB.bot(8) | compute/storeB
// B.top flies under A's compute; B.bot under A-stores+B-top compute. One
// full stall + one partial per 2 tiles (was 2 full), and the 20 address
// offsets (b-invariant) are computed once. Peak live ~126 VGPR;
// __launch_bounds__(256,4) forces <=128 -> keeps 16 waves/CU (guards
// against the R6 mode: 148 VGPR -> 8/CU -> collapse).
//
// Layout: (16,128,128,128) fp32 NHWC; C=128 -> 32 float4 groups, lane takes
// one c4 group: 32 consecutive lanes load 512 B contiguous per (row,col).

#define NEG_SLOPE 0.01f

__device__ __forceinline__ float lrelu(float v) {
    return fmaxf(v, NEG_SLOPE * v);  // slope < 1 => where(v>=0,v,s*v) == max
}

__device__ __forceinline__ float stencil(float a, float b, float c,
                                         float d, float e, float f,
                                         float g, float h, float i) {
    float up00 = 0.5625f * e + 0.1875f * (b + d) + 0.0625f * a;
    float up01 = 0.5625f * e + 0.1875f * (b + f) + 0.0625f * c;
    float up10 = 0.5625f * e + 0.1875f * (d + h) + 0.0625f * g;
    float up11 = 0.5625f * e + 0.1875f * (f + h) + 0.0625f * i;
    return 0.25f * (lrelu(up00) + lrelu(up01) + lrelu(up10) + lrelu(up11));
}

__device__ __forceinline__ float4 stencil4(const float4& a, const float4& b, const float4& c,
                                           const float4& d, const float4& e, const float4& f,
                                           const float4& g, const float4& h, const float4& i) {
    float4 o;
    o.x = stencil(a.x, b.x, c.x, d.x, e.x, f.x, g.x, h.x, i.x);
    o.y = stencil(a.y, b.y, c.y, d.y, e.y, f.y, g.y, h.y, i.y);
    o.z = stencil(a.z, b.z, c.z, d.z, e.z, f.z, g.z, h.z, i.z);
    o.w = stencil(a.w, b.w, c.w, d.w, e.w, f.w, g.w, h.w, i.w);
    return o;
}

// Named-register load halves (rows {ym,y0} / {y0+1,y3}) from base P.
#define LOAD_TOP(S, P)                                                        \
    const float4 S##00 = (P)[o00], S##01 = (P)[o01], S##02 = (P)[o02],        \
                 S##03 = (P)[o03],                                            \
                 S##10 = (P)[o10], S##11 = (P)[o11], S##12 = (P)[o12],        \
                 S##13 = (P)[o13];
#define LOAD_BOT(S, P)                                                        \
    const float4 S##20 = (P)[o20], S##21 = (P)[o21], S##22 = (P)[o22],        \
                 S##23 = (P)[o23],                                            \
                 S##30 = (P)[o30], S##31 = (P)[o31], S##32 = (P)[o32],        \
                 S##33 = (P)[o33];

#define CSTORE_SET(S, Q)                                                      \
    (Q)[s00] = stencil4(S##00, S##01, S##02, S##10, S##11, S##12,             \
                        S##20, S##21, S##22);                                 \
    (Q)[s01] = stencil4(S##01, S##02, S##03, S##11, S##12, S##13,             \
                        S##21, S##22, S##23);                                 \
    (Q)[s10] = stencil4(S##10, S##11, S##12, S##20, S##21, S##22,             \
                        S##30, S##31, S##32);                                 \
    (Q)[s11] = stencil4(S##11, S##12, S##13, S##21, S##22, S##23,             \
                        S##31, S##32, S##33);

__global__ __launch_bounds__(256, 4) void ActivationFilter_kernel(
        const float4* __restrict__ in, float4* __restrict__ out) {
    // thread -> (b0, py, px, c4): 8 * 64 * 64 * 32 = 1,048,576 threads;
    // each handles images b0 and b0+8. Block bit layout matches R3
    // (blk%8 = px_hi -> per-XCD vertical strip, py sequential).
    const int t  = blockIdx.x * 256 + threadIdx.x;
    const int c4 = t & 31;
    const int px = (t >> 5) & 63;
    const int py = (t >> 11) & 63;
    const int b0 = t >> 17;                   // 0..7

    const int x0 = px << 1, y0 = py << 1;
    const int xm = max(x0 - 1, 0), x3 = min(x0 + 2, 127);
    const int ym = max(y0 - 1, 0), y3 = min(y0 + 2, 127);

    // Per-image float4-unit offsets (b-invariant), computed once.
#define IOFF(Y, X) (((((Y) << 7) + (X)) << 5) + c4)
    const int o00 = IOFF(ym, xm),   o01 = IOFF(ym, x0),
              o02 = IOFF(ym, x0+1), o03 = IOFF(ym, x3);
    const int o10 = IOFF(y0, xm),   o11 = IOFF(y0, x0),
              o12 = IOFF(y0, x0+1), o13 = IOFF(y0, x3);
    const int o20 = IOFF(y0+1, xm),   o21 = IOFF(y0+1, x0),
              o22 = IOFF(y0+1, x0+1), o23 = IOFF(y0+1, x3);
    const int o30 = IOFF(y3, xm),   o31 = IOFF(y3, x0),
              o32 = IOFF(y3, x0+1), o33 = IOFF(y3, x3);
    const int s00 = IOFF(y0, x0),   s01 = IOFF(y0, x0+1);
    const int s10 = IOFF(y0+1, x0), s11 = IOFF(y0+1, x0+1);
#undef IOFF

    const int IMG  = 128 * 128 * 32;          // float4 units per image
    const float4* p0 = in  + b0 * IMG;
    float4*       q0 = out + b0 * IMG;
    const float4* p1 = p0 + (IMG << 3);       // image b0+8
    float4*       q1 = q0 + (IMG << 3);

    // ---- 1.5-deep pipeline, order pinned by sched_barriers ----
    LOAD_TOP(A, p0)
    LOAD_BOT(A, p0)
    __builtin_amdgcn_sched_barrier(0);
    LOAD_TOP(B, p1)                    // 8 loads fly under A's compute
    __builtin_amdgcn_sched_barrier(0);
    CSTORE_SET(A, q0)
    __builtin_amdgcn_sched_barrier(0);
    LOAD_BOT(B, p1)                    // 8 loads fly under A-stores/B-top math
    __builtin_amdgcn_sched_barrier(0);
    CSTORE_SET(B, q1)
}

extern "C" void kernel_launch(void* const* d_in, const int* in_sizes, int n_in,
                              void* d_out, int out_size, void* d_ws, size_t ws_size,
                              hipStream_t stream) {
    const float4* in = (const float4*)d_in[0];
    float4* out = (float4*)d_out;
    // 1,048,576 threads -> 4096 blocks of 256
    ActivationFilter_kernel<<<dim3(4096), dim3(256), 0, stream>>>(in, out);
}